// Round 4
// baseline (1002.230 us; speedup 1.0000x reference)
//
#include <hip/hip_runtime.h>
#include <hip/hip_bf16.h>

typedef short short8 __attribute__((ext_vector_type(8)));
typedef float f32x4 __attribute__((ext_vector_type(4)));
typedef unsigned short u16;
typedef unsigned int u32;

__device__ __forceinline__ u16 bf16rne(float f) {
    u32 u = __float_as_uint(f);
    u32 r = (u + 0x7fffu + ((u >> 16) & 1u)) >> 16;
    return (u16)r;
}
__device__ __forceinline__ float bf2f(u16 s) {
    return __uint_as_float(((u32)s) << 16);
}

// ---------------------------------------------------------------------------
// Weight prep: swizzle cg/vg weights into MFMA B-fragment order, bf16.
// Layer1: K=129 padded to 160 (5 k-tiles of 32), N=64 (4 n-tiles of 16).
// frag[nt][kt][lane][j] = W[kt*32 + (lane>>4)*8 + j][nt*16 + (lane&15)]
// ---------------------------------------------------------------------------
__global__ void prep_weights(const float* __restrict__ cgw1, const float* __restrict__ cgw2,
                             const float* __restrict__ vgw1, const float* __restrict__ vgw2,
                             u16* __restrict__ cg1s, u16* __restrict__ cg2s,
                             u16* __restrict__ vg1s, u16* __restrict__ vg2s) {
    const int total1 = 4 * 5 * 64 * 8;   // 10240
    for (int i = blockIdx.x * blockDim.x + threadIdx.x; i < total1;
         i += gridDim.x * blockDim.x) {
        int j = i & 7, lane = (i >> 3) & 63, g = i >> 9;
        int kt = g % 5, nt = g / 5;
        int k = kt * 32 + (lane >> 4) * 8 + j;
        int n = nt * 16 + (lane & 15);
        cg1s[i] = (k < 129) ? bf16rne(cgw1[k * 64 + n]) : (u16)0;
        vg1s[i] = (k < 129) ? bf16rne(vgw1[k * 64 + n]) : (u16)0;
    }
    const int total2 = 4 * 2 * 64 * 8;   // 4096
    for (int i = blockIdx.x * blockDim.x + threadIdx.x; i < total2;
         i += gridDim.x * blockDim.x) {
        int j = i & 7, lane = (i >> 3) & 63, g = i >> 9;
        int kt = g & 1, nt = g >> 1;
        int k = kt * 32 + (lane >> 4) * 8 + j;
        int n = nt * 16 + (lane & 15);
        cg2s[i] = bf16rne(cgw2[k * 64 + n]);
        vg2s[i] = bf16rne(vgw2[k * 64 + n]);
    }
}

// ---------------------------------------------------------------------------
// Input node MLP, wave-col-split: 64 nodes/block (node = lane), wave w owns
// output cols [16w,16w+16). Layers hand off via LDS (odd strides, no bank
// conflicts). Weight rows loaded as float4 (L1-hot, 16KB/layer).
// ---------------------------------------------------------------------------
template <int KIN>
__global__ __launch_bounds__(256) void node_mlp_in(
    const float* __restrict__ x, int n_nodes,
    const float* __restrict__ w1, const float* __restrict__ b1,
    const float* __restrict__ w2, const float* __restrict__ b2,
    u16* __restrict__ outbf) {
    __shared__ float Xin[64 * KIN];       // stride KIN (odd: 19 or 5)
    __shared__ float Xh[64 * 65];
    int tid = threadIdx.x, l = tid & 63, w = tid >> 6;
    int blk0 = blockIdx.x * 64;
    // coalesced stage of input rows
    for (int i = tid; i < 64 * KIN; i += 256) {
        int nd = i / KIN, k = i - nd * KIN;
        int gn = blk0 + nd; if (gn >= n_nodes) gn = n_nodes - 1;
        Xin[nd * KIN + k] = x[(size_t)gn * KIN + k];
    }
    __syncthreads();
    float h[16];
#pragma unroll
    for (int j = 0; j < 16; j++) h[j] = b1[w * 16 + j];
    for (int k = 0; k < KIN; k++) {
        float xk = Xin[l * KIN + k];
        const float4* wr = (const float4*)(w1 + k * 64 + w * 16);
        float4 w0 = wr[0], w1_ = wr[1], w2_ = wr[2], w3 = wr[3];
        h[0] = fmaf(xk, w0.x, h[0]);  h[1] = fmaf(xk, w0.y, h[1]);
        h[2] = fmaf(xk, w0.z, h[2]);  h[3] = fmaf(xk, w0.w, h[3]);
        h[4] = fmaf(xk, w1_.x, h[4]); h[5] = fmaf(xk, w1_.y, h[5]);
        h[6] = fmaf(xk, w1_.z, h[6]); h[7] = fmaf(xk, w1_.w, h[7]);
        h[8] = fmaf(xk, w2_.x, h[8]); h[9] = fmaf(xk, w2_.y, h[9]);
        h[10] = fmaf(xk, w2_.z, h[10]); h[11] = fmaf(xk, w2_.w, h[11]);
        h[12] = fmaf(xk, w3.x, h[12]); h[13] = fmaf(xk, w3.y, h[13]);
        h[14] = fmaf(xk, w3.z, h[14]); h[15] = fmaf(xk, w3.w, h[15]);
    }
#pragma unroll
    for (int j = 0; j < 16; j++) Xh[l * 65 + w * 16 + j] = fmaxf(h[j], 0.f);
    __syncthreads();
    float o[16];
#pragma unroll
    for (int j = 0; j < 16; j++) o[j] = b2[w * 16 + j];
    for (int k = 0; k < 64; k++) {
        float xk = Xh[l * 65 + k];
        const float4* wr = (const float4*)(w2 + k * 64 + w * 16);
        float4 w0 = wr[0], w1_ = wr[1], w2_ = wr[2], w3 = wr[3];
        o[0] = fmaf(xk, w0.x, o[0]);  o[1] = fmaf(xk, w0.y, o[1]);
        o[2] = fmaf(xk, w0.z, o[2]);  o[3] = fmaf(xk, w0.w, o[3]);
        o[4] = fmaf(xk, w1_.x, o[4]); o[5] = fmaf(xk, w1_.y, o[5]);
        o[6] = fmaf(xk, w1_.z, o[6]); o[7] = fmaf(xk, w1_.w, o[7]);
        o[8] = fmaf(xk, w2_.x, o[8]); o[9] = fmaf(xk, w2_.y, o[9]);
        o[10] = fmaf(xk, w2_.z, o[10]); o[11] = fmaf(xk, w2_.w, o[11]);
        o[12] = fmaf(xk, w3.x, o[12]); o[13] = fmaf(xk, w3.y, o[13]);
        o[14] = fmaf(xk, w3.z, o[14]); o[15] = fmaf(xk, w3.w, o[15]);
    }
    if (blk0 + l < n_nodes) {
        u32* op = (u32*)(outbf + (size_t)(blk0 + l) * 64 + w * 16);
#pragma unroll
        for (int j = 0; j < 16; j += 2) {
            u32 lo = bf16rne(fmaxf(o[j], 0.f));
            u32 hi = bf16rne(fmaxf(o[j + 1], 0.f));
            op[j >> 1] = lo | (hi << 16);
        }
    }
}

// ---------------------------------------------------------------------------
// Edge conv, wave-per-n-tile, NO prefetch (R3's spilled to scratch).
// Per tile: gather -> sync -> L1 MFMA -> sync -> L2 MFMA + atomics.
// ---------------------------------------------------------------------------
#define AROW 168   // 160 K-pad + 8 bank-pad (bf16 elems, 16B-multiple)
#define HROW 72

__global__ __launch_bounds__(256, 4) void edge_conv(
    const u16* __restrict__ u_feat, const u16* __restrict__ v_feat,
    const int* __restrict__ u_idx, const int* __restrict__ v_idx,
    const float* __restrict__ e_val,
    const u16* __restrict__ w1s, const u16* __restrict__ w2s,
    const float* __restrict__ b1, const float* __restrict__ b2,
    float* __restrict__ agg, int n_tiles) {
    __shared__ __align__(16) u16 A[64 * AROW];
    __shared__ __align__(16) u16 Hs[64 * HROW];

    int tid = threadIdx.x;
    int lane = tid & 63;
    int w = tid >> 6;
    int l15 = lane & 15, lq = lane >> 4;
    int cch = tid & 15, e0 = tid >> 4;   // gather role: fixed chunk, 4 edges

    // zero the K-pad columns (129..167) once; never rewritten afterwards
    for (int i = tid; i < 64 * (AROW - 129); i += 256) {
        int r = i / (AROW - 129);
        int cc = 129 + (i - r * (AROW - 129));
        A[r * AROW + cc] = 0;
    }

    // this wave's weight fragments (n-tile = w): 28 VGPRs
    short8 w1f[5], w2f[2];
#pragma unroll
    for (int kt = 0; kt < 5; kt++)
        w1f[kt] = *(const short8*)(w1s + ((w * 5 + kt) * 64 + lane) * 8);
#pragma unroll
    for (int kt = 0; kt < 2; kt++)
        w2f[kt] = *(const short8*)(w2s + ((w * 2 + kt) * 64 + lane) * 8);
    float b1v = b1[w * 16 + l15];
    float b2v = b2[w * 16 + l15];

    const int gcol = (cch < 8) ? cch * 8 : 64 + (cch - 8) * 8;
    __syncthreads();

    for (int tile = blockIdx.x; tile < n_tiles; tile += gridDim.x) {
        // ---- gather (direct; hazard vs prev L1 reads of A covered by the
        //      barrier after L1) ----
#pragma unroll
        for (int t = 0; t < 4; t++) {
            int e = e0 + t * 16;
            int ge = tile * 64 + e;
            const u16* src = (cch < 8)
                ? (u_feat + (size_t)u_idx[ge] * 64 + cch * 8)
                : (v_feat + (size_t)v_idx[ge] * 64 + (cch - 8) * 8);
            *(uint4*)(&A[e * AROW + gcol]) = *(const uint4*)src;
            if (cch == 0) A[e * AROW + 128] = bf16rne(e_val[ge]);
        }
        __syncthreads();

        // ---- layer 1: wave w computes H[:, 16w:16w+16) for 64 edges ----
#pragma unroll
        for (int mt = 0; mt < 4; mt++) {
            short8 a1[5];
#pragma unroll
            for (int kt = 0; kt < 5; kt++)
                a1[kt] = *(const short8*)(&A[(mt * 16 + l15) * AROW + kt * 32 + lq * 8]);
            f32x4 acc = {0.f, 0.f, 0.f, 0.f};
#pragma unroll
            for (int kt = 0; kt < 5; kt++)
                acc = __builtin_amdgcn_mfma_f32_16x16x32_bf16(a1[kt], w1f[kt], acc, 0, 0, 0);
#pragma unroll
            for (int r = 0; r < 4; r++) {
                float hv = fmaxf(acc[r] + b1v, 0.f);
                Hs[(mt * 16 + lq * 4 + r) * HROW + w * 16 + l15] = bf16rne(hv);
            }
        }
        __syncthreads();

        // ---- layer 2: wave w computes G[:, 16w:16w+16), atomic into agg ----
#pragma unroll
        for (int mt = 0; mt < 4; mt++) {
            short8 a2[2];
#pragma unroll
            for (int kt = 0; kt < 2; kt++)
                a2[kt] = *(const short8*)(&Hs[(mt * 16 + l15) * HROW + kt * 32 + lq * 8]);
            f32x4 acc = {0.f, 0.f, 0.f, 0.f};
#pragma unroll
            for (int kt = 0; kt < 2; kt++)
                acc = __builtin_amdgcn_mfma_f32_16x16x32_bf16(a2[kt], w2f[kt], acc, 0, 0, 0);
#pragma unroll
            for (int r = 0; r < 4; r++) {
                float gv = fmaxf(acc[r] + b2v, 0.f);
                int ue = u_idx[tile * 64 + mt * 16 + lq * 4 + r];
                __hip_atomic_fetch_add(&agg[(size_t)ue * 64 + w * 16 + l15], gv,
                                       __ATOMIC_RELAXED, __HIP_MEMORY_SCOPE_AGENT);
            }
        }
        // no barrier here: next gather writes A only; all L1 A-reads were
        // barriered above, and next-iter sync precedes next L1.
    }
}

// ---------------------------------------------------------------------------
// f-MLP, wave-col-split: concat(u_bf16[64], agg_f32[64]) -> 64 -> 64, bf16 out.
// ---------------------------------------------------------------------------
__global__ __launch_bounds__(256) void node_mlp_f(
    const u16* __restrict__ ubf, const float* __restrict__ agg, int n_nodes,
    const float* __restrict__ w1, const float* __restrict__ b1,
    const float* __restrict__ w2, const float* __restrict__ b2,
    u16* __restrict__ outbf) {
    __shared__ float Xin[64 * 129];
    __shared__ float Xh[64 * 65];
    int tid = threadIdx.x, l = tid & 63, w = tid >> 6;
    int blk0 = blockIdx.x * 64;
    for (int i = tid; i < 64 * 64; i += 256) {
        int nd = i >> 6, k = i & 63;
        int gn = blk0 + nd; if (gn >= n_nodes) gn = n_nodes - 1;
        Xin[nd * 129 + k] = bf2f(ubf[(size_t)gn * 64 + k]);
        Xin[nd * 129 + 64 + k] = agg[(size_t)gn * 64 + k];
    }
    __syncthreads();
    float h[16];
#pragma unroll
    for (int j = 0; j < 16; j++) h[j] = b1[w * 16 + j];
    for (int k = 0; k < 128; k++) {
        float xk = Xin[l * 129 + k];
        const float4* wr = (const float4*)(w1 + k * 64 + w * 16);
        float4 w0 = wr[0], w1_ = wr[1], w2_ = wr[2], w3 = wr[3];
        h[0] = fmaf(xk, w0.x, h[0]);  h[1] = fmaf(xk, w0.y, h[1]);
        h[2] = fmaf(xk, w0.z, h[2]);  h[3] = fmaf(xk, w0.w, h[3]);
        h[4] = fmaf(xk, w1_.x, h[4]); h[5] = fmaf(xk, w1_.y, h[5]);
        h[6] = fmaf(xk, w1_.z, h[6]); h[7] = fmaf(xk, w1_.w, h[7]);
        h[8] = fmaf(xk, w2_.x, h[8]); h[9] = fmaf(xk, w2_.y, h[9]);
        h[10] = fmaf(xk, w2_.z, h[10]); h[11] = fmaf(xk, w2_.w, h[11]);
        h[12] = fmaf(xk, w3.x, h[12]); h[13] = fmaf(xk, w3.y, h[13]);
        h[14] = fmaf(xk, w3.z, h[14]); h[15] = fmaf(xk, w3.w, h[15]);
    }
#pragma unroll
    for (int j = 0; j < 16; j++) Xh[l * 65 + w * 16 + j] = fmaxf(h[j], 0.f);
    __syncthreads();
    float o[16];
#pragma unroll
    for (int j = 0; j < 16; j++) o[j] = b2[w * 16 + j];
    for (int k = 0; k < 64; k++) {
        float xk = Xh[l * 65 + k];
        const float4* wr = (const float4*)(w2 + k * 64 + w * 16);
        float4 w0 = wr[0], w1_ = wr[1], w2_ = wr[2], w3 = wr[3];
        o[0] = fmaf(xk, w0.x, o[0]);  o[1] = fmaf(xk, w0.y, o[1]);
        o[2] = fmaf(xk, w0.z, o[2]);  o[3] = fmaf(xk, w0.w, o[3]);
        o[4] = fmaf(xk, w1_.x, o[4]); o[5] = fmaf(xk, w1_.y, o[5]);
        o[6] = fmaf(xk, w1_.z, o[6]); o[7] = fmaf(xk, w1_.w, o[7]);
        o[8] = fmaf(xk, w2_.x, o[8]); o[9] = fmaf(xk, w2_.y, o[9]);
        o[10] = fmaf(xk, w2_.z, o[10]); o[11] = fmaf(xk, w2_.w, o[11]);
        o[12] = fmaf(xk, w3.x, o[12]); o[13] = fmaf(xk, w3.y, o[13]);
        o[14] = fmaf(xk, w3.z, o[14]); o[15] = fmaf(xk, w3.w, o[15]);
    }
    if (blk0 + l < n_nodes) {
        u32* op = (u32*)(outbf + (size_t)(blk0 + l) * 64 + w * 16);
#pragma unroll
        for (int j = 0; j < 16; j += 2) {
            u32 lo = bf16rne(fmaxf(o[j], 0.f));
            u32 hi = bf16rne(fmaxf(o[j + 1], 0.f));
            op[j >> 1] = lo | (hi << 16);
        }
    }
}

// ---------------------------------------------------------------------------
// v-side f-MLP + tail, wave-col-split. vf: concat(v1,agg)->64->64 (=v2);
// tail: relu(v2@tw1+tb1)@tw2+tb2 -> sigmoid. Wave w computes tail-out cols
// {2w, 2w+1}. LDS: Xin (129-stride) doubles as the v2relu buffer.
// ---------------------------------------------------------------------------
__global__ __launch_bounds__(256) void node_mlp_vf_tail(
    const u16* __restrict__ vbf, const float* __restrict__ agg, int n_nodes,
    const float* __restrict__ w1, const float* __restrict__ b1,
    const float* __restrict__ w2, const float* __restrict__ b2,
    const float* __restrict__ tw1, const float* __restrict__ tb1,
    const float* __restrict__ tw2, const float* __restrict__ tb2,
    float* __restrict__ out) {
    __shared__ float Xin[64 * 129];
    __shared__ float Xh[64 * 65];
    int tid = threadIdx.x, l = tid & 63, w = tid >> 6;
    int blk0 = blockIdx.x * 64;
    for (int i = tid; i < 64 * 64; i += 256) {
        int nd = i >> 6, k = i & 63;
        int gn = blk0 + nd; if (gn >= n_nodes) gn = n_nodes - 1;
        Xin[nd * 129 + k] = bf2f(vbf[(size_t)gn * 64 + k]);
        Xin[nd * 129 + 64 + k] = agg[(size_t)gn * 64 + k];
    }
    __syncthreads();
    float h[16];
#pragma unroll
    for (int j = 0; j < 16; j++) h[j] = b1[w * 16 + j];
    for (int k = 0; k < 128; k++) {
        float xk = Xin[l * 129 + k];
        const float4* wr = (const float4*)(w1 + k * 64 + w * 16);
        float4 w0 = wr[0], w1_ = wr[1], w2_ = wr[2], w3 = wr[3];
        h[0] = fmaf(xk, w0.x, h[0]);  h[1] = fmaf(xk, w0.y, h[1]);
        h[2] = fmaf(xk, w0.z, h[2]);  h[3] = fmaf(xk, w0.w, h[3]);
        h[4] = fmaf(xk, w1_.x, h[4]); h[5] = fmaf(xk, w1_.y, h[5]);
        h[6] = fmaf(xk, w1_.z, h[6]); h[7] = fmaf(xk, w1_.w, h[7]);
        h[8] = fmaf(xk, w2_.x, h[8]); h[9] = fmaf(xk, w2_.y, h[9]);
        h[10] = fmaf(xk, w2_.z, h[10]); h[11] = fmaf(xk, w2_.w, h[11]);
        h[12] = fmaf(xk, w3.x, h[12]); h[13] = fmaf(xk, w3.y, h[13]);
        h[14] = fmaf(xk, w3.z, h[14]); h[15] = fmaf(xk, w3.w, h[15]);
    }
#pragma unroll
    for (int j = 0; j < 16; j++) Xh[l * 65 + w * 16 + j] = fmaxf(h[j], 0.f);
    __syncthreads();
    // layer 2 -> relu(v2) into Xin (reuse; all Xin reads finished pre-barrier)
    float o[16];
#pragma unroll
    for (int j = 0; j < 16; j++) o[j] = b2[w * 16 + j];
    for (int k = 0; k < 64; k++) {
        float xk = Xh[l * 65 + k];
        const float4* wr = (const float4*)(w2 + k * 64 + w * 16);
        float4 w0 = wr[0], w1_ = wr[1], w2_ = wr[2], w3 = wr[3];
        o[0] = fmaf(xk, w0.x, o[0]);  o[1] = fmaf(xk, w0.y, o[1]);
        o[2] = fmaf(xk, w0.z, o[2]);  o[3] = fmaf(xk, w0.w, o[3]);
        o[4] = fmaf(xk, w1_.x, o[4]); o[5] = fmaf(xk, w1_.y, o[5]);
        o[6] = fmaf(xk, w1_.z, o[6]); o[7] = fmaf(xk, w1_.w, o[7]);
        o[8] = fmaf(xk, w2_.x, o[8]); o[9] = fmaf(xk, w2_.y, o[9]);
        o[10] = fmaf(xk, w2_.z, o[10]); o[11] = fmaf(xk, w2_.w, o[11]);
        o[12] = fmaf(xk, w3.x, o[12]); o[13] = fmaf(xk, w3.y, o[13]);
        o[14] = fmaf(xk, w3.z, o[14]); o[15] = fmaf(xk, w3.w, o[15]);
    }
    __syncthreads();
#pragma unroll
    for (int j = 0; j < 16; j++) Xin[l * 129 + w * 16 + j] = fmaxf(o[j], 0.f);
    __syncthreads();
    // tail layer 1 -> relu into Xh
    float t[16];
#pragma unroll
    for (int j = 0; j < 16; j++) t[j] = tb1[w * 16 + j];
    for (int k = 0; k < 64; k++) {
        float xk = Xin[l * 129 + k];
        const float4* wr = (const float4*)(tw1 + k * 64 + w * 16);
        float4 w0 = wr[0], w1_ = wr[1], w2_ = wr[2], w3 = wr[3];
        t[0] = fmaf(xk, w0.x, t[0]);  t[1] = fmaf(xk, w0.y, t[1]);
        t[2] = fmaf(xk, w0.z, t[2]);  t[3] = fmaf(xk, w0.w, t[3]);
        t[4] = fmaf(xk, w1_.x, t[4]); t[5] = fmaf(xk, w1_.y, t[5]);
        t[6] = fmaf(xk, w1_.z, t[6]); t[7] = fmaf(xk, w1_.w, t[7]);
        t[8] = fmaf(xk, w2_.x, t[8]); t[9] = fmaf(xk, w2_.y, t[9]);
        t[10] = fmaf(xk, w2_.z, t[10]); t[11] = fmaf(xk, w2_.w, t[11]);
        t[12] = fmaf(xk, w3.x, t[12]); t[13] = fmaf(xk, w3.y, t[13]);
        t[14] = fmaf(xk, w3.z, t[14]); t[15] = fmaf(xk, w3.w, t[15]);
    }
    __syncthreads();
#pragma unroll
    for (int j = 0; j < 16; j++) Xh[l * 65 + w * 16 + j] = fmaxf(t[j], 0.f);
    __syncthreads();
    // tail layer 2: wave w computes out cols {2w, 2w+1}; sigmoid
    float s0 = tb2[2 * w], s1 = tb2[2 * w + 1];
    for (int k = 0; k < 64; k++) {
        float xk = Xh[l * 65 + k];
        float2 wp = *(const float2*)(tw2 + k * 8 + 2 * w);
        s0 = fmaf(xk, wp.x, s0);
        s1 = fmaf(xk, wp.y, s1);
    }
    if (blk0 + l < n_nodes) {
        float2 r;
        r.x = 1.f / (1.f + __expf(-s0));
        r.y = 1.f / (1.f + __expf(-s1));
        *(float2*)(out + (size_t)(blk0 + l) * 8 + 2 * w) = r;
    }
}

extern "C" void kernel_launch(void* const* d_in, const int* in_sizes, int n_in,
                              void* d_out, int out_size, void* d_ws, size_t ws_size,
                              hipStream_t stream) {
    const float* v        = (const float*)d_in[0];
    const float* c        = (const float*)d_in[1];
    const int*   cons_idx = (const int*)d_in[2];
    const int*   var_idx  = (const int*)d_in[3];
    const float* e_val    = (const float*)d_in[4];
    const float* ev_w1 = (const float*)d_in[5],  *ev_b1 = (const float*)d_in[6];
    const float* ev_w2 = (const float*)d_in[7],  *ev_b2 = (const float*)d_in[8];
    const float* ec_w1 = (const float*)d_in[9],  *ec_b1 = (const float*)d_in[10];
    const float* ec_w2 = (const float*)d_in[11], *ec_b2 = (const float*)d_in[12];
    const float* cg_w1 = (const float*)d_in[13], *cg_b1 = (const float*)d_in[14];
    const float* cg_w2 = (const float*)d_in[15], *cg_b2 = (const float*)d_in[16];
    const float* cf_w1 = (const float*)d_in[17], *cf_b1 = (const float*)d_in[18];
    const float* cf_w2 = (const float*)d_in[19], *cf_b2 = (const float*)d_in[20];
    const float* vg_w1 = (const float*)d_in[21], *vg_b1 = (const float*)d_in[22];
    const float* vg_w2 = (const float*)d_in[23], *vg_b2 = (const float*)d_in[24];
    const float* vf_w1 = (const float*)d_in[25], *vf_b1 = (const float*)d_in[26];
    const float* vf_w2 = (const float*)d_in[27], *vf_b2 = (const float*)d_in[28];
    const float* t_w1  = (const float*)d_in[29], *t_b1  = (const float*)d_in[30];
    const float* t_w2  = (const float*)d_in[31], *t_b2  = (const float*)d_in[32];

    const int NV = in_sizes[0] / 19;
    const int NC = in_sizes[1] / 5;
    const int NE = in_sizes[4];

    char* ws = (char*)d_ws;
    size_t off = 0;
    u16* v1bf = (u16*)(ws + off); off += (size_t)NV * 64 * 2;
    u16* c1bf = (u16*)(ws + off); off += (size_t)NC * 64 * 2;
    u16* c2bf = (u16*)(ws + off); off += (size_t)NC * 64 * 2;
    float* agg_c = (float*)(ws + off); off += (size_t)NC * 64 * 4;
    float* agg_v = (float*)(ws + off); off += (size_t)NV * 64 * 4;
    u16* cg1s = (u16*)(ws + off); off += 10240 * 2;
    u16* cg2s = (u16*)(ws + off); off += 4096 * 2;
    u16* vg1s = (u16*)(ws + off); off += 10240 * 2;
    u16* vg2s = (u16*)(ws + off); off += 4096 * 2;

    prep_weights<<<40, 256, 0, stream>>>(cg_w1, cg_w2, vg_w1, vg_w2,
                                         cg1s, cg2s, vg1s, vg2s);
    node_mlp_in<19><<<(NV + 63) / 64, 256, 0, stream>>>(
        v, NV, ev_w1, ev_b1, ev_w2, ev_b2, v1bf);
    node_mlp_in<5><<<(NC + 63) / 64, 256, 0, stream>>>(
        c, NC, ec_w1, ec_b1, ec_w2, ec_b2, c1bf);

    hipMemsetAsync(agg_c, 0, (size_t)NC * 64 * 4, stream);
    edge_conv<<<1280, 256, 0, stream>>>(c1bf, v1bf, cons_idx, var_idx, e_val,
                                        cg1s, cg2s, cg_b1, cg_b2, agg_c, NE / 64);
    node_mlp_f<<<(NC + 63) / 64, 256, 0, stream>>>(
        c1bf, agg_c, NC, cf_w1, cf_b1, cf_w2, cf_b2, c2bf);

    hipMemsetAsync(agg_v, 0, (size_t)NV * 64 * 4, stream);
    edge_conv<<<1280, 256, 0, stream>>>(v1bf, c2bf, var_idx, cons_idx, e_val,
                                        vg1s, vg2s, vg_b1, vg_b2, agg_v, NE / 64);
    node_mlp_vf_tail<<<(NV + 63) / 64, 256, 0, stream>>>(
        v1bf, agg_v, NV, vf_w1, vf_b1, vf_w2, vf_b2,
        t_w1, t_b1, t_w2, t_b2, (float*)d_out);
}

// Round 5
// 647.222 us; speedup vs baseline: 1.5485x; 1.5485x over previous
//
#include <hip/hip_runtime.h>
#include <hip/hip_bf16.h>

typedef short short8 __attribute__((ext_vector_type(8)));
typedef float f32x4 __attribute__((ext_vector_type(4)));
typedef unsigned short u16;
typedef unsigned int u32;

__device__ __forceinline__ u16 bf16rne(float f) {
    u32 u = __float_as_uint(f);
    u32 r = (u + 0x7fffu + ((u >> 16) & 1u)) >> 16;
    return (u16)r;
}
__device__ __forceinline__ float bf2f(u16 s) {
    return __uint_as_float(((u32)s) << 16);
}

// ---------------------------------------------------------------------------
// Weight swizzle into MFMA B-fragment order, bf16. For W[K x 64]:
// frag[i], i = ((nt*KT + kt)*64 + lane)*8 + j
//   = W[kt*32 + (lane>>4)*8 + j][nt*16 + (lane&15)], zero if k >= K.
// ---------------------------------------------------------------------------
__device__ __forceinline__ void swz(const float* __restrict__ src,
                                    u16* __restrict__ dst, int K, int KT,
                                    int tid0, int stride) {
    int total = 4 * KT * 512;
    for (int i = tid0; i < total; i += stride) {
        int j = i & 7, lane = (i >> 3) & 63, g = i >> 9;
        int kt = g % KT;  // nt = g / KT implicit in layout
        int k = kt * 32 + (lane >> 4) * 8 + j;
        int n = (g / KT) * 16 + (lane & 15);
        dst[i] = (k < K) ? bf16rne(src[k * 64 + n]) : (u16)0;
    }
}

__global__ void prep_weights(
    const float* ev1, const float* ev2, const float* ec1, const float* ec2,
    const float* cg1, const float* cg2, const float* cf1, const float* cf2,
    const float* vg1, const float* vg2, const float* vf1, const float* vf2,
    const float* t1,
    u16* dev1, u16* dev2, u16* dec1, u16* dec2, u16* dcg1, u16* dcg2,
    u16* dcf1, u16* dcf2, u16* dvg1, u16* dvg2, u16* dvf1, u16* dvf2,
    u16* dt1) {
    int tid0 = blockIdx.x * blockDim.x + threadIdx.x;
    int st = gridDim.x * blockDim.x;
    swz(ev1, dev1, 19, 1, tid0, st);
    swz(ev2, dev2, 64, 2, tid0, st);
    swz(ec1, dec1, 5, 1, tid0, st);
    swz(ec2, dec2, 64, 2, tid0, st);
    swz(cg1, dcg1, 129, 5, tid0, st);
    swz(cg2, dcg2, 64, 2, tid0, st);
    swz(cf1, dcf1, 128, 4, tid0, st);
    swz(cf2, dcf2, 64, 2, tid0, st);
    swz(vg1, dvg1, 129, 5, tid0, st);
    swz(vg2, dvg2, 64, 2, tid0, st);
    swz(vf1, dvf1, 128, 4, tid0, st);
    swz(vf2, dvf2, 64, 2, tid0, st);
    swz(t1, dt1, 64, 2, tid0, st);
}

// ---------------------------------------------------------------------------
// Generic MFMA layer: A[64 x KT*32] (u16, stride SA) @ Wfrag -> relu -> bf16
// into H (stride 72). Wave w owns output cols [16w, 16w+16).
// ---------------------------------------------------------------------------
template <int KT, int SA>
__device__ __forceinline__ void mfma_layer(const u16* __restrict__ Asrc,
                                           const short8* wf, float bv,
                                           u16* __restrict__ Hdst,
                                           int l15, int lq, int w) {
#pragma unroll
    for (int mt = 0; mt < 4; mt++) {
        f32x4 acc = {0.f, 0.f, 0.f, 0.f};
#pragma unroll
        for (int kt = 0; kt < KT; kt++) {
            short8 a = *(const short8*)(Asrc + (mt * 16 + l15) * SA + kt * 32 + lq * 8);
            acc = __builtin_amdgcn_mfma_f32_16x16x32_bf16(a, wf[kt], acc, 0, 0, 0);
        }
#pragma unroll
        for (int r = 0; r < 4; r++)
            Hdst[(mt * 16 + lq * 4 + r) * 72 + w * 16 + l15] =
                bf16rne(fmaxf(acc[r] + bv, 0.f));
    }
}

// ---------------------------------------------------------------------------
// Input node MLP (MFMA): x[KIN] -> 64 -> 64, relu/relu, bf16 out.
// 64 nodes/block; K padded to 32 (1 k-tile).
// ---------------------------------------------------------------------------
template <int KIN>
__global__ __launch_bounds__(256, 4) void node_mlp_in(
    const float* __restrict__ x, int n_nodes,
    const u16* __restrict__ w1s, const float* __restrict__ b1,
    const u16* __restrict__ w2s, const float* __restrict__ b2,
    u16* __restrict__ outbf) {
    __shared__ __align__(16) u16 A[64 * 40];
    __shared__ __align__(16) u16 H1[64 * 72];
    __shared__ __align__(16) u16 H2[64 * 72];
    int tid = threadIdx.x, l = tid & 63, w = tid >> 6;
    int l15 = l & 15, lq = l >> 4;
    int blk0 = blockIdx.x * 64;
    // zero pad cols [KIN,40)
    const int PW = 40 - KIN;
    for (int i = tid; i < 64 * PW; i += 256) {
        int r = i / PW, cc = KIN + (i - r * PW);
        A[r * 40 + cc] = 0;
    }
    // fill data cols
    for (int i = tid; i < 64 * KIN; i += 256) {
        int r = i / KIN, k = i - r * KIN;
        int gn = blk0 + r; if (gn >= n_nodes) gn = n_nodes - 1;
        A[r * 40 + k] = bf16rne(x[(size_t)gn * KIN + k]);
    }
    short8 w1f[1], w2f[2];
    w1f[0] = *(const short8*)(w1s + ((w * 1 + 0) * 64 + l) * 8);
#pragma unroll
    for (int kt = 0; kt < 2; kt++)
        w2f[kt] = *(const short8*)(w2s + ((w * 2 + kt) * 64 + l) * 8);
    float b1v = b1[w * 16 + l15], b2v = b2[w * 16 + l15];
    __syncthreads();
    mfma_layer<1, 40>(A, w1f, b1v, H1, l15, lq, w);
    __syncthreads();
    mfma_layer<2, 72>(H1, w2f, b2v, H2, l15, lq, w);
    __syncthreads();
    for (int i = tid; i < 512; i += 256) {
        int r = i >> 3, c = i & 7;
        if (blk0 + r < n_nodes)
            *(uint4*)(outbf + (size_t)(blk0 + r) * 64 + c * 8) =
                *(const uint4*)(H2 + r * 72 + c * 8);
    }
}

// ---------------------------------------------------------------------------
// Shared staging for f-MLPs: A[64 x 200] bf16 = [u(64) | agg_hi(64) |
// agg_residual(64) | 8 pad]; residual keeps agg at ~fp32 precision through
// layer 1 (weight fragments for k-tiles 4,5 reuse k-tiles 2,3).
// ---------------------------------------------------------------------------
__device__ __forceinline__ void stage_concat_res(
    const u16* __restrict__ ubf, const float* __restrict__ agg,
    int blk0, int n_nodes, u16* __restrict__ A, int tid) {
    for (int i = tid; i < 64 * 24; i += 256) {
        int nd = i / 24, c = i - nd * 24;
        int gn = blk0 + nd; if (gn >= n_nodes) gn = n_nodes - 1;
        if (c < 8) {
            *(uint4*)(A + nd * 200 + c * 8) =
                *(const uint4*)(ubf + (size_t)gn * 64 + c * 8);
        } else {
            int q = c - 8;
            float4 av = *(const float4*)(agg + (size_t)gn * 64 + q * 4);
            u16 h0 = bf16rne(av.x), h1 = bf16rne(av.y);
            u16 h2 = bf16rne(av.z), h3 = bf16rne(av.w);
            uint2 hi;
            hi.x = (u32)h0 | ((u32)h1 << 16);
            hi.y = (u32)h2 | ((u32)h3 << 16);
            *(uint2*)(A + nd * 200 + 64 + q * 4) = hi;
            uint2 rs;
            rs.x = (u32)bf16rne(av.x - bf2f(h0)) | ((u32)bf16rne(av.y - bf2f(h1)) << 16);
            rs.y = (u32)bf16rne(av.z - bf2f(h2)) | ((u32)bf16rne(av.w - bf2f(h3)) << 16);
            *(uint2*)(A + nd * 200 + 128 + q * 4) = rs;
        }
    }
}

// ---------------------------------------------------------------------------
// c-side f-MLP (MFMA): concat(c1, agg_hi, agg_res) -> 64 -> 64, bf16 out.
// L2 output staged C-layout into the (dead) A region, then coalesced store.
// ---------------------------------------------------------------------------
__global__ __launch_bounds__(256, 2) void node_mlp_f(
    const u16* __restrict__ ubf, const float* __restrict__ agg, int n_nodes,
    const u16* __restrict__ w1s, const float* __restrict__ b1,
    const u16* __restrict__ w2s, const float* __restrict__ b2,
    u16* __restrict__ outbf) {
    __shared__ __align__(16) u16 A[64 * 200];
    __shared__ __align__(16) u16 H1[64 * 72];
    int tid = threadIdx.x, l = tid & 63, w = tid >> 6;
    int l15 = l & 15, lq = l >> 4;
    int blk0 = blockIdx.x * 64;
    stage_concat_res(ubf, agg, blk0, n_nodes, A, tid);
    short8 w1f[6], w2f[2];
#pragma unroll
    for (int kt = 0; kt < 4; kt++)
        w1f[kt] = *(const short8*)(w1s + ((w * 4 + kt) * 64 + l) * 8);
    w1f[4] = w1f[2];   // residual cols reuse W1 rows 64..127
    w1f[5] = w1f[3];
#pragma unroll
    for (int kt = 0; kt < 2; kt++)
        w2f[kt] = *(const short8*)(w2s + ((w * 2 + kt) * 64 + l) * 8);
    float b1v = b1[w * 16 + l15], b2v = b2[w * 16 + l15];
    __syncthreads();
    mfma_layer<6, 200>(A, w1f, b1v, H1, l15, lq, w);
    __syncthreads();
    mfma_layer<2, 72>(H1, w2f, b2v, A, l15, lq, w);   // A region dead: reuse
    __syncthreads();
    for (int i = tid; i < 512; i += 256) {
        int r = i >> 3, c = i & 7;
        if (blk0 + r < n_nodes)
            *(uint4*)(outbf + (size_t)(blk0 + r) * 64 + c * 8) =
                *(const uint4*)(A + r * 72 + c * 8);
    }
}

// ---------------------------------------------------------------------------
// v-side f-MLP + tail (MFMA): concat(v1,agg_hi,agg_res)->64->64 (=v2),
// tail L1 MFMA -> f32 LDS, tail L2 (N=8) VALU f32 + sigmoid.
// ---------------------------------------------------------------------------
__global__ __launch_bounds__(256, 2) void node_mlp_vf_tail(
    const u16* __restrict__ vbf, const float* __restrict__ agg, int n_nodes,
    const u16* __restrict__ w1s, const float* __restrict__ b1,
    const u16* __restrict__ w2s, const float* __restrict__ b2,
    const u16* __restrict__ t1s, const float* __restrict__ tb1,
    const float* __restrict__ tw2, const float* __restrict__ tb2,
    float* __restrict__ out) {
    __shared__ __align__(16) char smem[64 * 200 * 2 + 2 * 64 * 72 * 2];
    u16* A = (u16*)smem;            // 25600 B; later reused as XF (f32)
    float* XF = (float*)smem;       // stride 65 (16640 B <= 25600)
    u16* H1 = (u16*)(smem + 25600);
    u16* H2 = (u16*)(smem + 25600 + 9216);
    int tid = threadIdx.x, l = tid & 63, w = tid >> 6;
    int l15 = l & 15, lq = l >> 4;
    int blk0 = blockIdx.x * 64;
    stage_concat_res(vbf, agg, blk0, n_nodes, A, tid);
    short8 w1f[6], w2f[2], t1f[2];
#pragma unroll
    for (int kt = 0; kt < 4; kt++)
        w1f[kt] = *(const short8*)(w1s + ((w * 4 + kt) * 64 + l) * 8);
    w1f[4] = w1f[2];
    w1f[5] = w1f[3];
#pragma unroll
    for (int kt = 0; kt < 2; kt++) {
        w2f[kt] = *(const short8*)(w2s + ((w * 2 + kt) * 64 + l) * 8);
        t1f[kt] = *(const short8*)(t1s + ((w * 2 + kt) * 64 + l) * 8);
    }
    float b1v = b1[w * 16 + l15], b2v = b2[w * 16 + l15];
    float tb1v = tb1[w * 16 + l15];
    __syncthreads();
    mfma_layer<6, 200>(A, w1f, b1v, H1, l15, lq, w);
    __syncthreads();
    mfma_layer<2, 72>(H1, w2f, b2v, H2, l15, lq, w);   // v2 (relu, bf16)
    __syncthreads();
    // tail layer 1: H2 @ t1f -> relu -> f32 XF (A region dead since L1)
#pragma unroll
    for (int mt = 0; mt < 4; mt++) {
        f32x4 acc = {0.f, 0.f, 0.f, 0.f};
#pragma unroll
        for (int kt = 0; kt < 2; kt++) {
            short8 a = *(const short8*)(H2 + (mt * 16 + l15) * 72 + kt * 32 + lq * 8);
            acc = __builtin_amdgcn_mfma_f32_16x16x32_bf16(a, t1f[kt], acc, 0, 0, 0);
        }
#pragma unroll
        for (int r = 0; r < 4; r++)
            XF[(mt * 16 + lq * 4 + r) * 65 + w * 16 + l15] =
                fmaxf(acc[r] + tb1v, 0.f);
    }
    __syncthreads();
    // tail layer 2: wave w computes out cols {2w,2w+1}; f32 VALU; sigmoid
    float s0 = tb2[2 * w], s1 = tb2[2 * w + 1];
    for (int k = 0; k < 64; k++) {
        float xk = XF[l * 65 + k];
        float2 wp = *(const float2*)(tw2 + k * 8 + 2 * w);
        s0 = fmaf(xk, wp.x, s0);
        s1 = fmaf(xk, wp.y, s1);
    }
    if (blk0 + l < n_nodes) {
        float2 r;
        r.x = 1.f / (1.f + __expf(-s0));
        r.y = 1.f / (1.f + __expf(-s1));
        *(float2*)(out + (size_t)(blk0 + l) * 8 + 2 * w) = r;
    }
}

// ---------------------------------------------------------------------------
// Edge conv (unchanged from R4): wave-per-n-tile, 2 barriers/tile,
// atomicAdd epilogue.
// ---------------------------------------------------------------------------
#define AROW 168
#define HROW 72

__global__ __launch_bounds__(256, 4) void edge_conv(
    const u16* __restrict__ u_feat, const u16* __restrict__ v_feat,
    const int* __restrict__ u_idx, const int* __restrict__ v_idx,
    const float* __restrict__ e_val,
    const u16* __restrict__ w1s, const u16* __restrict__ w2s,
    const float* __restrict__ b1, const float* __restrict__ b2,
    float* __restrict__ agg, int n_tiles) {
    __shared__ __align__(16) u16 A[64 * AROW];
    __shared__ __align__(16) u16 Hs[64 * HROW];

    int tid = threadIdx.x;
    int lane = tid & 63;
    int w = tid >> 6;
    int l15 = lane & 15, lq = lane >> 4;
    int cch = tid & 15, e0 = tid >> 4;

    for (int i = tid; i < 64 * (AROW - 129); i += 256) {
        int r = i / (AROW - 129);
        int cc = 129 + (i - r * (AROW - 129));
        A[r * AROW + cc] = 0;
    }

    short8 w1f[5], w2f[2];
#pragma unroll
    for (int kt = 0; kt < 5; kt++)
        w1f[kt] = *(const short8*)(w1s + ((w * 5 + kt) * 64 + lane) * 8);
#pragma unroll
    for (int kt = 0; kt < 2; kt++)
        w2f[kt] = *(const short8*)(w2s + ((w * 2 + kt) * 64 + lane) * 8);
    float b1v = b1[w * 16 + l15];
    float b2v = b2[w * 16 + l15];

    const int gcol = (cch < 8) ? cch * 8 : 64 + (cch - 8) * 8;
    __syncthreads();

    for (int tile = blockIdx.x; tile < n_tiles; tile += gridDim.x) {
#pragma unroll
        for (int t = 0; t < 4; t++) {
            int e = e0 + t * 16;
            int ge = tile * 64 + e;
            const u16* src = (cch < 8)
                ? (u_feat + (size_t)u_idx[ge] * 64 + cch * 8)
                : (v_feat + (size_t)v_idx[ge] * 64 + (cch - 8) * 8);
            *(uint4*)(&A[e * AROW + gcol]) = *(const uint4*)src;
            if (cch == 0) A[e * AROW + 128] = bf16rne(e_val[ge]);
        }
        __syncthreads();

#pragma unroll
        for (int mt = 0; mt < 4; mt++) {
            short8 a1[5];
#pragma unroll
            for (int kt = 0; kt < 5; kt++)
                a1[kt] = *(const short8*)(&A[(mt * 16 + l15) * AROW + kt * 32 + lq * 8]);
            f32x4 acc = {0.f, 0.f, 0.f, 0.f};
#pragma unroll
            for (int kt = 0; kt < 5; kt++)
                acc = __builtin_amdgcn_mfma_f32_16x16x32_bf16(a1[kt], w1f[kt], acc, 0, 0, 0);
#pragma unroll
            for (int r = 0; r < 4; r++) {
                float hv = fmaxf(acc[r] + b1v, 0.f);
                Hs[(mt * 16 + lq * 4 + r) * HROW + w * 16 + l15] = bf16rne(hv);
            }
        }
        __syncthreads();

#pragma unroll
        for (int mt = 0; mt < 4; mt++) {
            short8 a2[2];
#pragma unroll
            for (int kt = 0; kt < 2; kt++)
                a2[kt] = *(const short8*)(&Hs[(mt * 16 + l15) * HROW + kt * 32 + lq * 8]);
            f32x4 acc = {0.f, 0.f, 0.f, 0.f};
#pragma unroll
            for (int kt = 0; kt < 2; kt++)
                acc = __builtin_amdgcn_mfma_f32_16x16x32_bf16(a2[kt], w2f[kt], acc, 0, 0, 0);
#pragma unroll
            for (int r = 0; r < 4; r++) {
                float gv = fmaxf(acc[r] + b2v, 0.f);
                int ue = u_idx[tile * 64 + mt * 16 + lq * 4 + r];
                __hip_atomic_fetch_add(&agg[(size_t)ue * 64 + w * 16 + l15], gv,
                                       __ATOMIC_RELAXED, __HIP_MEMORY_SCOPE_AGENT);
            }
        }
    }
}

extern "C" void kernel_launch(void* const* d_in, const int* in_sizes, int n_in,
                              void* d_out, int out_size, void* d_ws, size_t ws_size,
                              hipStream_t stream) {
    const float* v        = (const float*)d_in[0];
    const float* c        = (const float*)d_in[1];
    const int*   cons_idx = (const int*)d_in[2];
    const int*   var_idx  = (const int*)d_in[3];
    const float* e_val    = (const float*)d_in[4];
    const float* ev_w1 = (const float*)d_in[5],  *ev_b1 = (const float*)d_in[6];
    const float* ev_w2 = (const float*)d_in[7],  *ev_b2 = (const float*)d_in[8];
    const float* ec_w1 = (const float*)d_in[9],  *ec_b1 = (const float*)d_in[10];
    const float* ec_w2 = (const float*)d_in[11], *ec_b2 = (const float*)d_in[12];
    const float* cg_w1 = (const float*)d_in[13], *cg_b1 = (const float*)d_in[14];
    const float* cg_w2 = (const float*)d_in[15], *cg_b2 = (const float*)d_in[16];
    const float* cf_w1 = (const float*)d_in[17], *cf_b1 = (const float*)d_in[18];
    const float* cf_w2 = (const float*)d_in[19], *cf_b2 = (const float*)d_in[20];
    const float* vg_w1 = (const float*)d_in[21], *vg_b1 = (const float*)d_in[22];
    const float* vg_w2 = (const float*)d_in[23], *vg_b2 = (const float*)d_in[24];
    const float* vf_w1 = (const float*)d_in[25], *vf_b1 = (const float*)d_in[26];
    const float* vf_w2 = (const float*)d_in[27], *vf_b2 = (const float*)d_in[28];
    const float* t_w1  = (const float*)d_in[29], *t_b1  = (const float*)d_in[30];
    const float* t_w2  = (const float*)d_in[31], *t_b2  = (const float*)d_in[32];

    const int NV = in_sizes[0] / 19;
    const int NC = in_sizes[1] / 5;
    const int NE = in_sizes[4];

    char* ws = (char*)d_ws;
    size_t off = 0;
    u16* v1bf = (u16*)(ws + off); off += (size_t)NV * 64 * 2;
    u16* c1bf = (u16*)(ws + off); off += (size_t)NC * 64 * 2;
    u16* c2bf = (u16*)(ws + off); off += (size_t)NC * 64 * 2;
    float* agg_c = (float*)(ws + off); off += (size_t)NC * 64 * 4;
    float* agg_v = (float*)(ws + off); off += (size_t)NV * 64 * 4;
    u16* ev1s = (u16*)(ws + off); off += 2048 * 2;
    u16* ev2s = (u16*)(ws + off); off += 4096 * 2;
    u16* ec1s = (u16*)(ws + off); off += 2048 * 2;
    u16* ec2s = (u16*)(ws + off); off += 4096 * 2;
    u16* cg1s = (u16*)(ws + off); off += 10240 * 2;
    u16* cg2s = (u16*)(ws + off); off += 4096 * 2;
    u16* cf1s = (u16*)(ws + off); off += 8192 * 2;
    u16* cf2s = (u16*)(ws + off); off += 4096 * 2;
    u16* vg1s = (u16*)(ws + off); off += 10240 * 2;
    u16* vg2s = (u16*)(ws + off); off += 4096 * 2;
    u16* vf1s = (u16*)(ws + off); off += 8192 * 2;
    u16* vf2s = (u16*)(ws + off); off += 4096 * 2;
    u16* t1s  = (u16*)(ws + off); off += 4096 * 2;

    prep_weights<<<40, 256, 0, stream>>>(
        ev_w1, ev_w2, ec_w1, ec_w2, cg_w1, cg_w2, cf_w1, cf_w2,
        vg_w1, vg_w2, vf_w1, vf_w2, t_w1,
        ev1s, ev2s, ec1s, ec2s, cg1s, cg2s, cf1s, cf2s,
        vg1s, vg2s, vf1s, vf2s, t1s);

    node_mlp_in<19><<<(NV + 63) / 64, 256, 0, stream>>>(
        v, NV, ev1s, ev_b1, ev2s, ev_b2, v1bf);
    node_mlp_in<5><<<(NC + 63) / 64, 256, 0, stream>>>(
        c, NC, ec1s, ec_b1, ec2s, ec_b2, c1bf);

    hipMemsetAsync(agg_c, 0, (size_t)NC * 64 * 4, stream);
    edge_conv<<<1280, 256, 0, stream>>>(c1bf, v1bf, cons_idx, var_idx, e_val,
                                        cg1s, cg2s, cg_b1, cg_b2, agg_c, NE / 64);
    node_mlp_f<<<(NC + 63) / 64, 256, 0, stream>>>(
        c1bf, agg_c, NC, cf1s, cf_b1, cf2s, cf_b2, c2bf);

    hipMemsetAsync(agg_v, 0, (size_t)NV * 64 * 4, stream);
    edge_conv<<<1280, 256, 0, stream>>>(v1bf, c2bf, var_idx, cons_idx, e_val,
                                        vg1s, vg2s, vg_b1, vg_b2, agg_v, NE / 64);
    node_mlp_vf_tail<<<(NV + 63) / 64, 256, 0, stream>>>(
        v1bf, agg_v, NV, vf1s, vf_b1, vf2s, vf_b2,
        t1s, t_b1, t_w2, t_b2, (float*)d_out);
}